// Round 1
// baseline (2334.699 us; speedup 1.0000x reference)
//
#include <hip/hip_runtime.h>
#include <stdint.h>

#define N_NODES 100000
#define N_REL 8
#define NP 16          // (relation, direction) pairs
#define D 256
#define E 262144       // 2^18 edges per pair
#define MP 100096      // N padded to multiple of 128
#define MTILES (MP / 128)

typedef __attribute__((ext_vector_type(8))) __bf16 bf16x8;
typedef __attribute__((ext_vector_type(4))) float f32x4;

__device__ __forceinline__ float bf2f(unsigned short u) {
    unsigned int v = ((unsigned int)u) << 16;
    return __builtin_bit_cast(float, v);
}
__device__ __forceinline__ unsigned short f2bf(float f) {
    unsigned int x = __builtin_bit_cast(unsigned int, f);
    unsigned int r = x + 0x7fffu + ((x >> 16) & 1u);   // RNE, finite inputs
    return (unsigned short)(r >> 16);
}
__device__ __forceinline__ void async16(const void* g, void* l) {
    __builtin_amdgcn_global_load_lds(
        (const __attribute__((address_space(1))) unsigned int*)g,
        (__attribute__((address_space(3))) unsigned int*)l, 16, 0, 0);
}

// ---- X (f32) -> bf16, 4 elems/thread ----
__global__ void k_conv_x(const float* __restrict__ X, unsigned short* __restrict__ Xb) {
    size_t base = ((size_t)blockIdx.x * blockDim.x + threadIdx.x) * 4;
    if (base >= (size_t)N_NODES * D) return;
    float4 v = *(const float4*)(X + base);
    ushort4 o;
    o.x = f2bf(v.x); o.y = f2bf(v.y); o.z = f2bf(v.z); o.w = f2bf(v.w);
    *(ushort4*)(Xb + base) = o;
}

// ---- W, W_t (f32 [p][k][n]) -> bf16 transposed WT[p][n][k] ----
__global__ void k_conv_w(const float* __restrict__ w, const float* __restrict__ wt,
                         unsigned short* __restrict__ WT) {
    int gid = blockIdx.x * blockDim.x + threadIdx.x;
    if (gid >= NP * D * D) return;
    int p = gid >> 16, k = (gid >> 8) & 255, n = gid & 255;
    const float* src = (p < N_REL) ? (w + ((size_t)p << 16)) : (wt + ((size_t)(p - N_REL) << 16));
    WT[((size_t)p << 16) + (n << 8) + k] = f2bf(src[(k << 8) + n]);
}

// ---- bw[p][j] = sum_k bias[p][k] * W[p][k][j], exact f32 ----
__global__ void k_bw(const float* __restrict__ bias, const float* __restrict__ bias_t,
                     const float* __restrict__ w, const float* __restrict__ wt,
                     float* __restrict__ bw) {
    int p = blockIdx.x, j = threadIdx.x;
    const float* b = (p < N_REL) ? bias + p * D : bias_t + (p - N_REL) * D;
    const float* W = (p < N_REL) ? w + ((size_t)p << 16) : wt + ((size_t)(p - N_REL) << 16);
    float acc = 0.f;
    for (int k = 0; k < D; ++k) acc += b[k] * W[(k << 8) + j];
    bw[p * D + j] = acc;
}

// ---- degree histogram ----
__global__ void k_count(const int* __restrict__ ar, const int* __restrict__ atr,
                        unsigned int* __restrict__ cnt) {
    int gid = blockIdx.x * blockDim.x + threadIdx.x;
    if (gid >= NP * E) return;
    int p = gid >> 18, e = gid & (E - 1);
    const int* rows = (p < N_REL) ? ar + (size_t)p * E : atr + (size_t)(p - N_REL) * E;
    atomicAdd(&cnt[(size_t)p * N_NODES + rows[e]], 1u);
}

// ---- exclusive scan per pair (16 blocks x 1024) -> off, cursor ----
__global__ void k_scan(const unsigned int* __restrict__ cnt, unsigned int* __restrict__ off,
                       unsigned int* __restrict__ cur) {
    __shared__ unsigned int sums[16];
    __shared__ unsigned int stot;
    int p = blockIdx.x, tid = threadIdx.x, lane = tid & 63, wv = tid >> 6;
    unsigned int base = 0;
    const unsigned int* c = cnt + (size_t)p * N_NODES;
    unsigned int* o  = off + (size_t)p * N_NODES;
    unsigned int* cu = cur + (size_t)p * N_NODES;
    for (int start = 0; start < N_NODES; start += 1024) {
        int idx = start + tid;
        unsigned int v = (idx < N_NODES) ? c[idx] : 0u;
        unsigned int x = v;
        #pragma unroll
        for (int d = 1; d < 64; d <<= 1) {
            unsigned int t = __shfl_up(x, d, 64);
            if (lane >= d) x += t;
        }
        if (lane == 63) sums[wv] = x;
        __syncthreads();
        if (tid == 0) {
            unsigned int run = 0;
            for (int i = 0; i < 16; ++i) { unsigned int t = sums[i]; sums[i] = run; run += t; }
            stot = run;
        }
        __syncthreads();
        unsigned int ex = base + sums[wv] + (x - v);
        if (idx < N_NODES) { o[idx] = ex; cu[idx] = ex; }
        base += stot;
        __syncthreads();
    }
}

// ---- scatter edges into CSR slots ----
__global__ void k_scatter(const int* __restrict__ ar, const int* __restrict__ ac,
                          const int* __restrict__ atr, const int* __restrict__ atc,
                          unsigned int* __restrict__ cur, unsigned int* __restrict__ csr) {
    int gid = blockIdx.x * blockDim.x + threadIdx.x;
    if (gid >= NP * E) return;
    int p = gid >> 18, e = gid & (E - 1);
    const int *rows, *cols;
    if (p < N_REL) { rows = ar + (size_t)p * E;  cols = ac + (size_t)p * E; }
    else           { rows = atr + (size_t)(p - N_REL) * E; cols = atc + (size_t)(p - N_REL) * E; }
    int r = rows[e];
    unsigned int slot = atomicAdd(&cur[(size_t)p * N_NODES + r], 1u);
    csr[(size_t)p * E + slot] = (unsigned int)cols[e];
}

// ---- aggregate: one wave per (pair, node): comp[n] = (1/deg) * sum X[c], bf16 out ----
__global__ void k_agg(const unsigned short* __restrict__ Xb, const unsigned int* __restrict__ cnt,
                      const unsigned int* __restrict__ off, const unsigned int* __restrict__ csr,
                      unsigned short* __restrict__ comp, int cs, int npairs) {
    int wg = blockIdx.x * 4 + (threadIdx.x >> 6);
    int lane = threadIdx.x & 63;
    if (wg >= npairs * MP) return;
    int lp = wg / MP;
    int n = wg - lp * MP;
    int p = cs + lp;
    float ax = 0.f, ay = 0.f, az = 0.f, aw = 0.f;
    if (n < N_NODES) {
        unsigned int deg = cnt[(size_t)p * N_NODES + n];
        if (deg) {
            unsigned int b = off[(size_t)p * N_NODES + n];
            const unsigned int* cp = csr + (size_t)p * E + b;
            for (unsigned int e2 = 0; e2 < deg; ++e2) {
                unsigned int c = cp[e2];
                ushort4 u = *(const ushort4*)(Xb + (size_t)c * D + lane * 4);
                ax += bf2f(u.x); ay += bf2f(u.y); az += bf2f(u.z); aw += bf2f(u.w);
            }
            float s = 1.0f / (float)deg;
            ax *= s; ay *= s; az *= s; aw *= s;
        }
    }
    ushort4 o;
    o.x = f2bf(ax); o.y = f2bf(ay); o.z = f2bf(az); o.w = f2bf(aw);
    *(ushort4*)(comp + ((size_t)lp * MP + n) * D + lane * 4) = o;
}

// ---- batched GEMM: out[M,256] (+)= sum_lp comp[lp] @ W[cs+lp]  (m97-style) ----
__global__ __launch_bounds__(256) void k_gemm(const unsigned short* __restrict__ comp,
                                              const unsigned short* __restrict__ WT,
                                              float* __restrict__ out, int cs, int npairs,
                                              int first) {
    __shared__ unsigned short As[128 * 64];   // [m][k]
    __shared__ unsigned short Bs[128 * 64];   // [n][k]
    int bid = blockIdx.x;
    int mt = bid >> 1, nt = bid & 1;
    int rowBase = mt * 128, colBase = nt * 128;
    int tid = threadIdx.x, wv = tid >> 6, lane = tid & 63;

    int sRow[4], ldsOff[4];
    #pragma unroll
    for (int jj = 0; jj < 4; ++jj) {
        int j = wv * 4 + jj;
        sRow[jj] = j * 8 + (lane >> 3);
        ldsOff[jj] = j * 512 + lane * 8;
    }
    int sCol = (lane & 7) * 8;

    int M0 = (wv & 1) * 64, N0 = (wv >> 1) * 64;
    int fr = lane & 15, quad = lane >> 4;

    f32x4 acc[4][4];
    #pragma unroll
    for (int i = 0; i < 4; ++i)
        #pragma unroll
        for (int j = 0; j < 4; ++j) { f32x4 z = {0.f, 0.f, 0.f, 0.f}; acc[i][j] = z; }

    for (int lp = 0; lp < npairs; ++lp) {
        const unsigned short* Ab = comp + ((size_t)lp * MP + rowBase) * D;
        const unsigned short* Bb = WT + (((size_t)(cs + lp)) << 16) + (size_t)colBase * D;
        for (int k0 = 0; k0 < D; k0 += 64) {
            __syncthreads();
            #pragma unroll
            for (int jj = 0; jj < 4; ++jj) {
                async16(Ab + (size_t)sRow[jj] * D + k0 + sCol, &As[ldsOff[jj]]);
                async16(Bb + (size_t)sRow[jj] * D + k0 + sCol, &Bs[ldsOff[jj]]);
            }
            __syncthreads();
            #pragma unroll
            for (int kk = 0; kk < 64; kk += 32) {
                bf16x8 af[4], bfr[4];
                #pragma unroll
                for (int i = 0; i < 4; ++i) {
                    af[i]  = *(const bf16x8*)(&As[(M0 + i * 16 + fr) * 64 + kk + quad * 8]);
                    bfr[i] = *(const bf16x8*)(&Bs[(N0 + i * 16 + fr) * 64 + kk + quad * 8]);
                }
                #pragma unroll
                for (int i = 0; i < 4; ++i)
                    #pragma unroll
                    for (int j = 0; j < 4; ++j)
                        acc[i][j] = __builtin_amdgcn_mfma_f32_16x16x32_bf16(af[i], bfr[j], acc[i][j], 0, 0, 0);
            }
        }
    }
    // epilogue: C mapping col=lane&15, row=quad*4+reg
    #pragma unroll
    for (int i = 0; i < 4; ++i) {
        int r0 = rowBase + M0 + i * 16 + quad * 4;
        #pragma unroll
        for (int j = 0; j < 4; ++j) {
            int col = colBase + N0 + j * 16 + fr;
            #pragma unroll
            for (int r = 0; r < 4; ++r) {
                int row = r0 + r;
                if (row < N_NODES) {
                    size_t idx = (size_t)row * D + col;
                    if (first) out[idx] = acc[i][j][r];
                    else       out[idx] += acc[i][j][r];
                }
            }
        }
    }
}

// ---- epilogue: out = (out + sum_p 1{deg_p>0} bw[p]) / max(full_deg,1) ----
__global__ void k_epi(float* __restrict__ out, const unsigned int* __restrict__ cnt,
                      const float* __restrict__ bw) {
    int node = blockIdx.x * 4 + (threadIdx.x >> 6);
    int lane = threadIdx.x & 63;
    unsigned int c = 0;
    if (lane < NP) c = cnt[(size_t)lane * N_NODES + node];
    unsigned long long m = __ballot(c > 0);
    int fd = __popcll(m);
    float invf = fd ? 1.0f / (float)fd : 1.0f;
    float bx = 0.f, by = 0.f, bz = 0.f, bwv = 0.f;
    #pragma unroll
    for (int p = 0; p < NP; ++p) {
        if ((m >> p) & 1ull) {
            float4 b = *(const float4*)(bw + p * D + lane * 4);
            bx += b.x; by += b.y; bz += b.z; bwv += b.w;
        }
    }
    float4 o = *(float4*)(out + (size_t)node * D + lane * 4);
    o.x = (o.x + bx) * invf; o.y = (o.y + by) * invf;
    o.z = (o.z + bz) * invf; o.w = (o.w + bwv) * invf;
    *(float4*)(out + (size_t)node * D + lane * 4) = o;
}

extern "C" void kernel_launch(void* const* d_in, const int* in_sizes, int n_in,
                              void* d_out, int out_size, void* d_ws, size_t ws_size,
                              hipStream_t stream) {
    (void)in_sizes; (void)n_in; (void)out_size;
    const float* X      = (const float*)d_in[0];
    const float* w      = (const float*)d_in[1];
    const float* bias   = (const float*)d_in[2];
    const float* wt     = (const float*)d_in[3];
    const float* bias_t = (const float*)d_in[4];
    const int* ar  = (const int*)d_in[5];
    const int* ac  = (const int*)d_in[6];
    const int* atr = (const int*)d_in[7];
    const int* atc = (const int*)d_in[8];
    float* out = (float*)d_out;

    char* ws = (char*)d_ws;
    size_t o = 0;
    auto alloc = [&](size_t bytes) -> char* {
        char* p = ws + o;
        o = (o + bytes + 255) & ~(size_t)255;
        return p;
    };
    unsigned short* Xb  = (unsigned short*)alloc((size_t)N_NODES * D * 2);
    unsigned short* WT  = (unsigned short*)alloc((size_t)NP * D * D * 2);
    float*          bw  = (float*)alloc((size_t)NP * D * 4);
    unsigned int*   cnt = (unsigned int*)alloc((size_t)NP * N_NODES * 4);
    unsigned int*   off = (unsigned int*)alloc((size_t)NP * N_NODES * 4);
    unsigned int*   cur = (unsigned int*)alloc((size_t)NP * N_NODES * 4);
    unsigned int*   csr = (unsigned int*)alloc((size_t)NP * E * 4);
    size_t fixed = o;
    size_t per = (size_t)MP * D * 2;   // already 256-aligned
    const int cands[5] = {16, 8, 4, 2, 1};
    int cp = 1;
    for (int i = 0; i < 5; ++i)
        if (fixed + (size_t)cands[i] * per <= ws_size) { cp = cands[i]; break; }
    unsigned short* comp = (unsigned short*)(ws + fixed);

    hipMemsetAsync(cnt, 0, (size_t)NP * N_NODES * 4, stream);
    k_conv_x<<<(N_NODES * D / 4 + 255) / 256, 256, 0, stream>>>(X, Xb);
    k_conv_w<<<NP * D * D / 256, 256, 0, stream>>>(w, wt, WT);
    k_bw<<<NP, 256, 0, stream>>>(bias, bias_t, w, wt, bw);
    k_count<<<NP * E / 256, 256, 0, stream>>>(ar, atr, cnt);
    k_scan<<<NP, 1024, 0, stream>>>(cnt, off, cur);
    k_scatter<<<NP * E / 256, 256, 0, stream>>>(ar, ac, atr, atc, cur, csr);
    for (int cs = 0; cs < NP; cs += cp) {
        k_agg<<<(cp * MP) / 4, 256, 0, stream>>>(Xb, cnt, off, csr, comp, cs, cp);
        k_gemm<<<MTILES * 2, 256, 0, stream>>>(comp, WT, out, cs, cp, cs == 0 ? 1 : 0);
    }
    k_epi<<<N_NODES / 4, 256, 0, stream>>>(out, cnt, bw);
}

// Round 2
// 2296.450 us; speedup vs baseline: 1.0167x; 1.0167x over previous
//
#include <hip/hip_runtime.h>
#include <stdint.h>

#define N_NODES 100000
#define N_REL 8
#define NP 16          // (relation, direction) pairs
#define D 256
#define E 262144       // 2^18 edges per pair
#define BM 64          // fused-kernel row tile
#define MT64 1563      // ceil(100000/64)
#define NCH 49         // scan chunks per pair (49*2048 >= 100000)

typedef __attribute__((ext_vector_type(8))) __bf16 bf16x8;
typedef __attribute__((ext_vector_type(4))) float f32x4;

__device__ __forceinline__ float bf2f(unsigned short u) {
    unsigned int v = ((unsigned int)u) << 16;
    return __builtin_bit_cast(float, v);
}
__device__ __forceinline__ unsigned short f2bf(float f) {
    unsigned int x = __builtin_bit_cast(unsigned int, f);
    unsigned int r = x + 0x7fffu + ((x >> 16) & 1u);   // RNE, finite inputs
    return (unsigned short)(r >> 16);
}
__device__ __forceinline__ void async16(const void* g, void* l) {
    __builtin_amdgcn_global_load_lds(
        (const __attribute__((address_space(1))) unsigned int*)g,
        (__attribute__((address_space(3))) unsigned int*)l, 16, 0, 0);
}

// ---- X (f32) -> bf16, 4 elems/thread ----
__global__ void k_conv_x(const float* __restrict__ X, unsigned short* __restrict__ Xb) {
    size_t base = ((size_t)blockIdx.x * blockDim.x + threadIdx.x) * 4;
    if (base >= (size_t)N_NODES * D) return;
    float4 v = *(const float4*)(X + base);
    ushort4 o;
    o.x = f2bf(v.x); o.y = f2bf(v.y); o.z = f2bf(v.z); o.w = f2bf(v.w);
    *(ushort4*)(Xb + base) = o;
}

// ---- W, W_t (f32 [p][k][n]) -> bf16 transposed WT[p][n][k], LDS-tiled ----
__global__ void k_conv_w(const float* __restrict__ w, const float* __restrict__ wt,
                         unsigned short* __restrict__ WT) {
    __shared__ unsigned short tile[64 * 65];
    int b = blockIdx.x;
    int p = b >> 4, t16 = b & 15;
    int k0 = (t16 >> 2) * 64, n0 = (t16 & 3) * 64;
    const float* src = (p < N_REL) ? (w + ((size_t)p << 16)) : (wt + ((size_t)(p - N_REL) << 16));
    int tid = threadIdx.x;
    #pragma unroll
    for (int pass = 0; pass < 16; ++pass) {
        int idx = pass * 256 + tid;
        int r = idx >> 6, c = idx & 63;            // r = k local, c = n local
        tile[c * 65 + r] = f2bf(src[(size_t)(k0 + r) * D + n0 + c]);
    }
    __syncthreads();
    unsigned short* dst = WT + ((size_t)p << 16);
    #pragma unroll
    for (int pass = 0; pass < 16; ++pass) {
        int idx = pass * 256 + tid;
        int rr = idx >> 6, cc = idx & 63;          // rr = n local, cc = k local
        dst[(size_t)(n0 + rr) * D + k0 + cc] = tile[rr * 65 + cc];
    }
}

// ---- bw[p][j] = sum_k bias[p][k] * W[p][k][j], exact f32 ----
__global__ void k_bw(const float* __restrict__ bias, const float* __restrict__ bias_t,
                     const float* __restrict__ w, const float* __restrict__ wt,
                     float* __restrict__ bw) {
    int p = blockIdx.x, j = threadIdx.x;
    const float* b = (p < N_REL) ? bias + p * D : bias_t + (p - N_REL) * D;
    const float* W = (p < N_REL) ? w + ((size_t)p << 16) : wt + ((size_t)(p - N_REL) << 16);
    float acc = 0.f;
    for (int k = 0; k < D; ++k) acc += b[k] * W[(k << 8) + j];
    bw[p * D + j] = acc;
}

// ---- XCD-affinity remap: pair p -> XCD p%8 (blockIdx%8 heuristic, perf-only) ----
__device__ __forceinline__ void remap_pe(int b, int tid, int& p, int& e) {
    int xcd = b & 7;
    int g = b >> 3;                 // 0..2047
    p = xcd + 8 * (g & 1);          // pairs {xcd, xcd+8}
    e = ((g >> 1) << 8) + tid;      // chunk*256 + tid
}

// ---- degree histogram (XCD-affine) ----
__global__ void k_count(const int* __restrict__ ar, const int* __restrict__ atr,
                        unsigned int* __restrict__ cnt) {
    int p, e;
    remap_pe(blockIdx.x, threadIdx.x, p, e);
    const int* rows = (p < N_REL) ? ar + (size_t)p * E : atr + (size_t)(p - N_REL) * E;
    atomicAdd(&cnt[(size_t)p * N_NODES + rows[e]], 1u);
}

// ---- scan phase A: per-chunk (2048) sums ----
__global__ void k_scanA(const unsigned int* __restrict__ cnt, unsigned int* __restrict__ part) {
    __shared__ unsigned int wsum[4];
    int b = blockIdx.x;
    int p = b / NCH, ch = b - p * NCH;
    int tid = threadIdx.x, lane = tid & 63, wv = tid >> 6;
    const unsigned int* c = cnt + (size_t)p * N_NODES;
    int base = ch * 2048 + tid * 8;
    unsigned int s = 0;
    #pragma unroll
    for (int i = 0; i < 8; ++i) { int idx = base + i; if (idx < N_NODES) s += c[idx]; }
    #pragma unroll
    for (int d = 32; d; d >>= 1) s += __shfl_down(s, d, 64);
    if (lane == 0) wsum[wv] = s;
    __syncthreads();
    if (tid == 0) part[b] = wsum[0] + wsum[1] + wsum[2] + wsum[3];
}

// ---- scan phase B: exclusive scan of chunk sums per pair ----
__global__ void k_scanB(unsigned int* __restrict__ part) {
    int p = threadIdx.x;
    if (p >= NP) return;
    unsigned int run = 0;
    for (int i = 0; i < NCH; ++i) {
        unsigned int t = part[p * NCH + i];
        part[p * NCH + i] = run;
        run += t;
    }
}

// ---- scan phase C: local exclusive scan + chunk base -> off, cur ----
__global__ void k_scanC(const unsigned int* __restrict__ cnt, const unsigned int* __restrict__ part,
                        unsigned int* __restrict__ off, unsigned int* __restrict__ cur) {
    __shared__ unsigned int wsum[4];
    __shared__ unsigned int wexc[4];
    int b = blockIdx.x;
    int p = b / NCH, ch = b - p * NCH;
    int tid = threadIdx.x, lane = tid & 63, wv = tid >> 6;
    const unsigned int* c = cnt + (size_t)p * N_NODES;
    int base = ch * 2048 + tid * 8;
    unsigned int v[8], s = 0;
    #pragma unroll
    for (int i = 0; i < 8; ++i) {
        int idx = base + i;
        v[i] = (idx < N_NODES) ? c[idx] : 0u;
        s += v[i];
    }
    unsigned int x = s;
    #pragma unroll
    for (int d = 1; d < 64; d <<= 1) {
        unsigned int t = __shfl_up(x, d, 64);
        if (lane >= d) x += t;
    }
    if (lane == 63) wsum[wv] = x;
    __syncthreads();
    if (tid == 0) {
        unsigned int run = 0;
        for (int i = 0; i < 4; ++i) { unsigned int t = wsum[i]; wexc[i] = run; run += t; }
    }
    __syncthreads();
    unsigned int run = part[b] + wexc[wv] + (x - s);
    #pragma unroll
    for (int i = 0; i < 8; ++i) {
        int idx = base + i;
        if (idx < N_NODES) {
            size_t g = (size_t)p * N_NODES + idx;
            off[g] = run; cur[g] = run;
        }
        run += v[i];
    }
}

// ---- scatter edges into CSR slots (XCD-affine) ----
__global__ void k_scatter(const int* __restrict__ ar, const int* __restrict__ ac,
                          const int* __restrict__ atr, const int* __restrict__ atc,
                          unsigned int* __restrict__ cur, unsigned int* __restrict__ csr) {
    int p, e;
    remap_pe(blockIdx.x, threadIdx.x, p, e);
    const int *rows, *cols;
    if (p < N_REL) { rows = ar + (size_t)p * E;  cols = ac + (size_t)p * E; }
    else           { rows = atr + (size_t)(p - N_REL) * E; cols = atc + (size_t)(p - N_REL) * E; }
    int r = rows[e];
    unsigned int slot = atomicAdd(&cur[(size_t)p * N_NODES + r], 1u);
    csr[(size_t)p * E + slot] = (unsigned int)cols[e];
}

// ---- fused aggregate + batched GEMM ----
// Block: 64 rows x 256 cols, 512 threads (8 waves, 2x4 of 32x64 tiles).
// Per pair: gather-aggregate A-tile (bf16) into LDS, then 4 K-panels of MFMA
// with async-staged B. Accumulates all 16 pairs in registers; writes out once.
__global__ __launch_bounds__(512, 4) void k_fused(
        const unsigned short* __restrict__ Xb, const unsigned int* __restrict__ cnt,
        const unsigned int* __restrict__ off, const unsigned int* __restrict__ csr,
        const unsigned short* __restrict__ WT, float* __restrict__ out) {
    __shared__ unsigned short At[BM * D];      // 32 KB, [m][k]
    __shared__ unsigned short Bs[D * 64];      // 32 KB, [n][k-panel]
    int rb = blockIdx.x * BM;
    int tid = threadIdx.x, wv = tid >> 6, lane = tid & 63;
    int fr = lane & 15, quad = lane >> 4;
    int M0 = (wv & 1) * 32;
    int N0 = (wv >> 1) * 64;
    int bn = (tid >> 3);            // 0..63: B staging row within pass group
    int bc = (lane & 7) * 8;        // B staging col (ushorts)

    f32x4 acc[2][4];
    #pragma unroll
    for (int i = 0; i < 2; ++i)
        #pragma unroll
        for (int j = 0; j < 4; ++j) { f32x4 z = {0.f, 0.f, 0.f, 0.f}; acc[i][j] = z; }

    for (int p = 0; p < NP; ++p) {
        __syncthreads();   // previous pair's MFMA done reading At
        // ---- aggregate phase: wave wv handles rows wv, wv+8, ... ----
        const unsigned int* cntp = cnt + (size_t)p * N_NODES;
        const unsigned int* offp = off + (size_t)p * N_NODES;
        const unsigned int* csrp = csr + (size_t)p * E;
        #pragma unroll
        for (int lr = wv; lr < BM; lr += 8) {
            int n = rb + lr;
            float ax = 0.f, ay = 0.f, az = 0.f, aw = 0.f;
            if (n < N_NODES) {
                unsigned int deg = cntp[n];
                if (deg) {
                    const unsigned int* cp = csrp + offp[n];
                    for (unsigned int e2 = 0; e2 < deg; ++e2) {
                        unsigned int c = cp[e2];
                        ushort4 u = *(const ushort4*)(Xb + ((size_t)c << 8) + lane * 4);
                        ax += bf2f(u.x); ay += bf2f(u.y); az += bf2f(u.z); aw += bf2f(u.w);
                    }
                    float s = 1.0f / (float)deg;
                    ax *= s; ay *= s; az *= s; aw *= s;
                }
            }
            ushort4 o;
            o.x = f2bf(ax); o.y = f2bf(ay); o.z = f2bf(az); o.w = f2bf(aw);
            *(ushort4*)(&At[lr * D + lane * 4]) = o;
        }
        // ---- GEMM phase ----
        const unsigned short* Bb = WT + ((size_t)p << 16);
        for (int k0 = 0; k0 < D; k0 += 64) {
            __syncthreads();   // At ready (first panel) / Bs consumed (later panels)
            #pragma unroll
            for (int jj = 0; jj < 4; ++jj) {
                int nrow = jj * 64 + bn;                      // 0..255
                async16(Bb + (size_t)nrow * D + k0 + bc,
                        &Bs[(size_t)nrow * 64 + bc]);
            }
            __syncthreads();   // Bs ready (vmcnt drained by barrier)
            #pragma unroll
            for (int kk = 0; kk < 64; kk += 32) {
                bf16x8 af[2], bfv[4];
                #pragma unroll
                for (int i = 0; i < 2; ++i)
                    af[i] = *(const bf16x8*)(&At[(M0 + i * 16 + fr) * D + k0 + kk + quad * 8]);
                #pragma unroll
                for (int j = 0; j < 4; ++j)
                    bfv[j] = *(const bf16x8*)(&Bs[(N0 + j * 16 + fr) * 64 + kk + quad * 8]);
                #pragma unroll
                for (int i = 0; i < 2; ++i)
                    #pragma unroll
                    for (int j = 0; j < 4; ++j)
                        acc[i][j] = __builtin_amdgcn_mfma_f32_16x16x32_bf16(af[i], bfv[j], acc[i][j], 0, 0, 0);
            }
        }
    }
    // epilogue: C mapping col=lane&15, row=quad*4+reg
    #pragma unroll
    for (int i = 0; i < 2; ++i) {
        int r0 = rb + M0 + i * 16 + quad * 4;
        #pragma unroll
        for (int j = 0; j < 4; ++j) {
            int col = N0 + j * 16 + fr;
            #pragma unroll
            for (int r = 0; r < 4; ++r) {
                int row = r0 + r;
                if (row < N_NODES) out[(size_t)row * D + col] = acc[i][j][r];
            }
        }
    }
}

// ---- epilogue: out = (out + sum_p 1{deg_p>0} bw[p]) / max(full_deg,1) ----
__global__ void k_epi(float* __restrict__ out, const unsigned int* __restrict__ cnt,
                      const float* __restrict__ bw) {
    int node = blockIdx.x * 4 + (threadIdx.x >> 6);
    int lane = threadIdx.x & 63;
    unsigned int c = 0;
    if (lane < NP) c = cnt[(size_t)lane * N_NODES + node];
    unsigned long long m = __ballot(c > 0);
    int fd = __popcll(m);
    float invf = fd ? 1.0f / (float)fd : 1.0f;
    float bx = 0.f, by = 0.f, bz = 0.f, bwv = 0.f;
    #pragma unroll
    for (int p = 0; p < NP; ++p) {
        if ((m >> p) & 1ull) {
            float4 b = *(const float4*)(bw + p * D + lane * 4);
            bx += b.x; by += b.y; bz += b.z; bwv += b.w;
        }
    }
    float4 o = *(float4*)(out + (size_t)node * D + lane * 4);
    o.x = (o.x + bx) * invf; o.y = (o.y + by) * invf;
    o.z = (o.z + bz) * invf; o.w = (o.w + bwv) * invf;
    *(float4*)(out + (size_t)node * D + lane * 4) = o;
}

extern "C" void kernel_launch(void* const* d_in, const int* in_sizes, int n_in,
                              void* d_out, int out_size, void* d_ws, size_t ws_size,
                              hipStream_t stream) {
    (void)in_sizes; (void)n_in; (void)out_size; (void)ws_size;
    const float* X      = (const float*)d_in[0];
    const float* w      = (const float*)d_in[1];
    const float* bias   = (const float*)d_in[2];
    const float* wt     = (const float*)d_in[3];
    const float* bias_t = (const float*)d_in[4];
    const int* ar  = (const int*)d_in[5];
    const int* ac  = (const int*)d_in[6];
    const int* atr = (const int*)d_in[7];
    const int* atc = (const int*)d_in[8];
    float* out = (float*)d_out;

    char* ws = (char*)d_ws;
    size_t o = 0;
    auto alloc = [&](size_t bytes) -> char* {
        char* p = ws + o;
        o = (o + bytes + 255) & ~(size_t)255;
        return p;
    };
    unsigned short* Xb   = (unsigned short*)alloc((size_t)N_NODES * D * 2);
    unsigned short* WT   = (unsigned short*)alloc((size_t)NP * D * D * 2);
    float*          bw   = (float*)alloc((size_t)NP * D * 4);
    unsigned int*   cnt  = (unsigned int*)alloc((size_t)NP * N_NODES * 4);
    unsigned int*   off  = (unsigned int*)alloc((size_t)NP * N_NODES * 4);
    unsigned int*   cur  = (unsigned int*)alloc((size_t)NP * N_NODES * 4);
    unsigned int*   csr  = (unsigned int*)alloc((size_t)NP * E * 4);
    unsigned int*   part = (unsigned int*)alloc((size_t)NP * NCH * 4);

    hipMemsetAsync(cnt, 0, (size_t)NP * N_NODES * 4, stream);
    k_conv_x<<<(N_NODES * D / 4 + 255) / 256, 256, 0, stream>>>(X, Xb);
    k_conv_w<<<NP * 16, 256, 0, stream>>>(w, wt, WT);
    k_bw<<<NP, 256, 0, stream>>>(bias, bias_t, w, wt, bw);
    k_count<<<NP * E / 256, 256, 0, stream>>>(ar, atr, cnt);
    k_scanA<<<NP * NCH, 256, 0, stream>>>(cnt, part);
    k_scanB<<<1, 64, 0, stream>>>(part);
    k_scanC<<<NP * NCH, 256, 0, stream>>>(cnt, part, off, cur);
    k_scatter<<<NP * E / 256, 256, 0, stream>>>(ar, ac, atr, atc, cur, csr);
    k_fused<<<MT64, 512, 0, stream>>>(Xb, cnt, off, csr, WT, out);
    k_epi<<<N_NODES / 4, 256, 0, stream>>>(out, cnt, bw);
}

// Round 3
// 2223.816 us; speedup vs baseline: 1.0499x; 1.0327x over previous
//
#include <hip/hip_runtime.h>
#include <stdint.h>

#define N_NODES 100000
#define N_REL 8
#define NP 16          // (relation, direction) pairs
#define D 256
#define E 262144       // 2^18 edges per pair
#define MP 100096      // N padded to multiple of 128
#define MT128 (MP / 128)
#define NCH 49         // scan chunks per pair (49*2048 >= 100000)

typedef __attribute__((ext_vector_type(8))) __bf16 bf16x8;
typedef __attribute__((ext_vector_type(4))) float f32x4;

__device__ __forceinline__ float bf2f(unsigned short u) {
    unsigned int v = ((unsigned int)u) << 16;
    return __builtin_bit_cast(float, v);
}
__device__ __forceinline__ unsigned short f2bf(float f) {
    unsigned int x = __builtin_bit_cast(unsigned int, f);
    unsigned int r = x + 0x7fffu + ((x >> 16) & 1u);   // RNE, finite inputs
    return (unsigned short)(r >> 16);
}
__device__ __forceinline__ void async16(const void* g, void* l) {
    __builtin_amdgcn_global_load_lds(
        (const __attribute__((address_space(1))) unsigned int*)g,
        (__attribute__((address_space(3))) unsigned int*)l, 16, 0, 0);
}

// ---- X (f32) -> bf16, 4 elems/thread ----
__global__ void k_conv_x(const float* __restrict__ X, unsigned short* __restrict__ Xb) {
    size_t base = ((size_t)blockIdx.x * blockDim.x + threadIdx.x) * 4;
    if (base >= (size_t)N_NODES * D) return;
    float4 v = *(const float4*)(X + base);
    ushort4 o;
    o.x = f2bf(v.x); o.y = f2bf(v.y); o.z = f2bf(v.z); o.w = f2bf(v.w);
    *(ushort4*)(Xb + base) = o;
}

// ---- W, W_t (f32 [p][k][n]) -> bf16 transposed WT[p][n][k], LDS-tiled ----
__global__ void k_conv_w(const float* __restrict__ w, const float* __restrict__ wt,
                         unsigned short* __restrict__ WT) {
    __shared__ unsigned short tile[64 * 65];
    int b = blockIdx.x;
    int p = b >> 4, t16 = b & 15;
    int k0 = (t16 >> 2) * 64, n0 = (t16 & 3) * 64;
    const float* src = (p < N_REL) ? (w + ((size_t)p << 16)) : (wt + ((size_t)(p - N_REL) << 16));
    int tid = threadIdx.x;
    #pragma unroll
    for (int pass = 0; pass < 16; ++pass) {
        int idx = pass * 256 + tid;
        int r = idx >> 6, c = idx & 63;            // r = k local, c = n local
        tile[c * 65 + r] = f2bf(src[(size_t)(k0 + r) * D + n0 + c]);
    }
    __syncthreads();
    unsigned short* dst = WT + ((size_t)p << 16);
    #pragma unroll
    for (int pass = 0; pass < 16; ++pass) {
        int idx = pass * 256 + tid;
        int rr = idx >> 6, cc = idx & 63;          // rr = n local, cc = k local
        dst[(size_t)(n0 + rr) * D + k0 + cc] = tile[rr * 65 + cc];
    }
}

// ---- bw[p][j] = sum_k bias[p][k] * W[p][k][j], exact f32 ----
__global__ void k_bw(const float* __restrict__ bias, const float* __restrict__ bias_t,
                     const float* __restrict__ w, const float* __restrict__ wt,
                     float* __restrict__ bw) {
    int p = blockIdx.x, j = threadIdx.x;
    const float* b = (p < N_REL) ? bias + p * D : bias_t + (p - N_REL) * D;
    const float* W = (p < N_REL) ? w + ((size_t)p << 16) : wt + ((size_t)(p - N_REL) << 16);
    float acc = 0.f;
    for (int k = 0; k < D; ++k) acc += b[k] * W[(k << 8) + j];
    bw[p * D + j] = acc;
}

// ---- XCD-affinity remap: pair p -> XCD p%8 (blockIdx%8 heuristic, perf-only) ----
__device__ __forceinline__ void remap_pe(int b, int tid, int& p, int& e) {
    int xcd = b & 7;
    int g = b >> 3;                 // 0..2047
    p = xcd + 8 * (g & 1);          // pairs {xcd, xcd+8}
    e = ((g >> 1) << 8) + tid;      // chunk*256 + tid
}

// ---- degree histogram (XCD-affine) ----
__global__ void k_count(const int* __restrict__ ar, const int* __restrict__ atr,
                        unsigned int* __restrict__ cnt) {
    int p, e;
    remap_pe(blockIdx.x, threadIdx.x, p, e);
    const int* rows = (p < N_REL) ? ar + (size_t)p * E : atr + (size_t)(p - N_REL) * E;
    atomicAdd(&cnt[(size_t)p * N_NODES + rows[e]], 1u);
}

// ---- scan phase A: per-chunk (2048) sums ----
__global__ void k_scanA(const unsigned int* __restrict__ cnt, unsigned int* __restrict__ part) {
    __shared__ unsigned int wsum[4];
    int b = blockIdx.x;
    int p = b / NCH, ch = b - p * NCH;
    int tid = threadIdx.x, lane = tid & 63, wv = tid >> 6;
    const unsigned int* c = cnt + (size_t)p * N_NODES;
    int base = ch * 2048 + tid * 8;
    unsigned int s = 0;
    #pragma unroll
    for (int i = 0; i < 8; ++i) { int idx = base + i; if (idx < N_NODES) s += c[idx]; }
    #pragma unroll
    for (int d = 32; d; d >>= 1) s += __shfl_down(s, d, 64);
    if (lane == 0) wsum[wv] = s;
    __syncthreads();
    if (tid == 0) part[b] = wsum[0] + wsum[1] + wsum[2] + wsum[3];
}

// ---- scan phase B: exclusive scan of chunk sums per pair ----
__global__ void k_scanB(unsigned int* __restrict__ part) {
    int p = threadIdx.x;
    if (p >= NP) return;
    unsigned int run = 0;
    for (int i = 0; i < NCH; ++i) {
        unsigned int t = part[p * NCH + i];
        part[p * NCH + i] = run;
        run += t;
    }
}

// ---- scan phase C: local exclusive scan + chunk base -> oc (off,deg), cur ----
__global__ void k_scanC(const unsigned int* __restrict__ cnt, const unsigned int* __restrict__ part,
                        uint2* __restrict__ oc, unsigned int* __restrict__ cur) {
    __shared__ unsigned int wsum[4];
    __shared__ unsigned int wexc[4];
    int b = blockIdx.x;
    int p = b / NCH, ch = b - p * NCH;
    int tid = threadIdx.x, lane = tid & 63, wv = tid >> 6;
    const unsigned int* c = cnt + (size_t)p * N_NODES;
    int base = ch * 2048 + tid * 8;
    unsigned int v[8], s = 0;
    #pragma unroll
    for (int i = 0; i < 8; ++i) {
        int idx = base + i;
        v[i] = (idx < N_NODES) ? c[idx] : 0u;
        s += v[i];
    }
    unsigned int x = s;
    #pragma unroll
    for (int d = 1; d < 64; d <<= 1) {
        unsigned int t = __shfl_up(x, d, 64);
        if (lane >= d) x += t;
    }
    if (lane == 63) wsum[wv] = x;
    __syncthreads();
    if (tid == 0) {
        unsigned int run = 0;
        for (int i = 0; i < 4; ++i) { unsigned int t = wsum[i]; wexc[i] = run; run += t; }
    }
    __syncthreads();
    unsigned int run = part[b] + wexc[wv] + (x - s);
    #pragma unroll
    for (int i = 0; i < 8; ++i) {
        int idx = base + i;
        if (idx < N_NODES) {
            size_t g = (size_t)p * N_NODES + idx;
            oc[g] = make_uint2(run, v[i]);
            cur[g] = run;
        }
        run += v[i];
    }
}

// ---- scatter edges into CSR slots (XCD-affine) ----
__global__ void k_scatter(const int* __restrict__ ar, const int* __restrict__ ac,
                          const int* __restrict__ atr, const int* __restrict__ atc,
                          unsigned int* __restrict__ cur, unsigned int* __restrict__ csr) {
    int p, e;
    remap_pe(blockIdx.x, threadIdx.x, p, e);
    const int *rows, *cols;
    if (p < N_REL) { rows = ar + (size_t)p * E;  cols = ac + (size_t)p * E; }
    else           { rows = atr + (size_t)(p - N_REL) * E; cols = atc + (size_t)(p - N_REL) * E; }
    int r = rows[e];
    unsigned int slot = atomicAdd(&cur[(size_t)p * N_NODES + r], 1u);
    csr[(size_t)p * E + slot] = (unsigned int)cols[e];
}

// ---- aggregate: one wave per (pair, node): comp[n] = (1/deg) * sum X[c], bf16 out ----
// Lane-parallel index fetch + shfl broadcast -> deg INDEPENDENT row loads in flight.
__global__ __launch_bounds__(256) void k_agg(
        const unsigned short* __restrict__ Xb, const uint2* __restrict__ oc,
        const unsigned int* __restrict__ csr, unsigned short* __restrict__ comp,
        int cs, int npairs) {
    int wid = blockIdx.x * 4 + (threadIdx.x >> 6);
    int lane = threadIdx.x & 63;
    if (wid >= npairs * MP) return;
    int lp = wid / MP;
    int n = wid - lp * MP;
    int p = cs + lp;
    float ax = 0.f, ay = 0.f, az = 0.f, aw = 0.f;
    if (n < N_NODES) {
        uint2 v = oc[(size_t)p * N_NODES + n];
        unsigned int b = v.x, deg = v.y;
        if (deg) {
            const unsigned int* cp = csr + (size_t)p * E + b;
            for (unsigned int e0 = 0; e0 < deg; e0 += 64) {
                unsigned int rem = deg - e0; if (rem > 64) rem = 64;
                unsigned int idx = (lane < rem) ? cp[e0 + lane] : 0u;
                for (unsigned int e2 = 0; e2 < rem; ++e2) {
                    unsigned int c = __shfl(idx, (int)e2, 64);
                    ushort4 u = *(const ushort4*)(Xb + ((size_t)c << 8) + (lane << 2));
                    ax += bf2f(u.x); ay += bf2f(u.y); az += bf2f(u.z); aw += bf2f(u.w);
                }
            }
            float s = 1.0f / (float)deg;
            ax *= s; ay *= s; az *= s; aw *= s;
        }
    }
    ushort4 o;
    o.x = f2bf(ax); o.y = f2bf(ay); o.z = f2bf(az); o.w = f2bf(aw);
    *(ushort4*)(comp + ((size_t)lp * MP + n) * D + (lane << 2)) = o;
}

// ---- batched GEMM: out[M,256] (+)= sum_lp comp[lp] @ W[cs+lp] ----
// 128x256 block tile, 8 waves (2M x 4N of 64x64). A read ONCE (full N in block).
// XOR chunk swizzle (phys = chunk ^ (row&7)) applied at global_load_lds source
// -> conflict-free ds_read_b128 (2 lanes/bank).
__global__ __launch_bounds__(512, 2) void k_gemm(
        const unsigned short* __restrict__ comp, const unsigned short* __restrict__ WT,
        float* __restrict__ out, int cs, int npairs, int first) {
    __shared__ unsigned short As[128 * 64];   // 16 KB  [row][phys-chunk]
    __shared__ unsigned short Bs[256 * 64];   // 32 KB
    int rb = blockIdx.x * 128;
    int tid = threadIdx.x, wv = tid >> 6, lane = tid & 63;
    int fr = lane & 15, quad = lane >> 4;
    int M0 = (wv & 1) * 64, N0 = (wv >> 1) * 64;

    f32x4 acc[4][4];
    #pragma unroll
    for (int i = 0; i < 4; ++i)
        #pragma unroll
        for (int j = 0; j < 4; ++j) { f32x4 z = {0.f, 0.f, 0.f, 0.f}; acc[i][j] = z; }

    for (int lp = 0; lp < npairs; ++lp) {
        const unsigned short* Ab = comp + ((size_t)lp * MP + rb) * D;
        const unsigned short* Bb = WT + ((size_t)(cs + lp) << 16);
        for (int k0 = 0; k0 < D; k0 += 64) {
            __syncthreads();                       // prev panel's ds_reads done
            #pragma unroll
            for (int pass = 0; pass < 2; ++pass) { // A: 128 rows x 8 chunks
                int L = pass * 512 + tid;
                int row = L >> 3, pc = L & 7, gc = pc ^ (row & 7);
                async16(Ab + (size_t)row * D + k0 + gc * 8, &As[L * 8]);
            }
            #pragma unroll
            for (int pass = 0; pass < 4; ++pass) { // B: 256 rows x 8 chunks
                int L = pass * 512 + tid;
                int row = L >> 3, pc = L & 7, gc = pc ^ (row & 7);
                async16(Bb + (size_t)row * D + k0 + gc * 8, &Bs[L * 8]);
            }
            __syncthreads();                       // staging complete (vmcnt drained)
            #pragma unroll
            for (int kk = 0; kk < 64; kk += 32) {
                int wc = (kk >> 3) + quad;         // wanted global chunk
                int pc = wc ^ (fr & 7);            // swizzled phys chunk
                bf16x8 af[4], bfv[4];
                #pragma unroll
                for (int i = 0; i < 4; ++i)
                    af[i] = *(const bf16x8*)(&As[(M0 + i * 16 + fr) * 64 + pc * 8]);
                #pragma unroll
                for (int j = 0; j < 4; ++j)
                    bfv[j] = *(const bf16x8*)(&Bs[(N0 + j * 16 + fr) * 64 + pc * 8]);
                #pragma unroll
                for (int i = 0; i < 4; ++i)
                    #pragma unroll
                    for (int j = 0; j < 4; ++j)
                        acc[i][j] = __builtin_amdgcn_mfma_f32_16x16x32_bf16(af[i], bfv[j], acc[i][j], 0, 0, 0);
            }
        }
    }
    // epilogue: C mapping col=lane&15, row=quad*4+reg
    #pragma unroll
    for (int i = 0; i < 4; ++i) {
        int r0 = rb + M0 + i * 16 + quad * 4;
        #pragma unroll
        for (int j = 0; j < 4; ++j) {
            int col = N0 + j * 16 + fr;
            #pragma unroll
            for (int r = 0; r < 4; ++r) {
                int row = r0 + r;
                if (row < N_NODES) {
                    size_t idx = (size_t)row * D + col;
                    if (first) out[idx] = acc[i][j][r];
                    else       out[idx] += acc[i][j][r];
                }
            }
        }
    }
}

// ---- epilogue: out = (out + sum_p 1{deg_p>0} bw[p]) / max(full_deg,1) ----
__global__ void k_epi(float* __restrict__ out, const unsigned int* __restrict__ cnt,
                      const float* __restrict__ bw) {
    int node = blockIdx.x * 4 + (threadIdx.x >> 6);
    int lane = threadIdx.x & 63;
    unsigned int c = 0;
    if (lane < NP) c = cnt[(size_t)lane * N_NODES + node];
    unsigned long long m = __ballot(c > 0);
    int fd = __popcll(m);
    float invf = fd ? 1.0f / (float)fd : 1.0f;
    float bx = 0.f, by = 0.f, bz = 0.f, bwv = 0.f;
    #pragma unroll
    for (int p = 0; p < NP; ++p) {
        if ((m >> p) & 1ull) {
            float4 b = *(const float4*)(bw + p * D + lane * 4);
            bx += b.x; by += b.y; bz += b.z; bwv += b.w;
        }
    }
    float4 o = *(float4*)(out + (size_t)node * D + lane * 4);
    o.x = (o.x + bx) * invf; o.y = (o.y + by) * invf;
    o.z = (o.z + bz) * invf; o.w = (o.w + bwv) * invf;
    *(float4*)(out + (size_t)node * D + lane * 4) = o;
}

extern "C" void kernel_launch(void* const* d_in, const int* in_sizes, int n_in,
                              void* d_out, int out_size, void* d_ws, size_t ws_size,
                              hipStream_t stream) {
    (void)in_sizes; (void)n_in; (void)out_size;
    const float* X      = (const float*)d_in[0];
    const float* w      = (const float*)d_in[1];
    const float* bias   = (const float*)d_in[2];
    const float* wt     = (const float*)d_in[3];
    const float* bias_t = (const float*)d_in[4];
    const int* ar  = (const int*)d_in[5];
    const int* ac  = (const int*)d_in[6];
    const int* atr = (const int*)d_in[7];
    const int* atc = (const int*)d_in[8];
    float* out = (float*)d_out;

    char* ws = (char*)d_ws;
    size_t o = 0;
    auto alloc = [&](size_t bytes) -> char* {
        char* p = ws + o;
        o = (o + bytes + 255) & ~(size_t)255;
        return p;
    };
    unsigned short* Xb   = (unsigned short*)alloc((size_t)N_NODES * D * 2);
    unsigned short* WT   = (unsigned short*)alloc((size_t)NP * D * D * 2);
    float*          bw   = (float*)alloc((size_t)NP * D * 4);
    unsigned int*   cnt  = (unsigned int*)alloc((size_t)NP * N_NODES * 4);
    uint2*          oc   = (uint2*)alloc((size_t)NP * N_NODES * 8);
    unsigned int*   cur  = (unsigned int*)alloc((size_t)NP * N_NODES * 4);
    unsigned int*   csr  = (unsigned int*)alloc((size_t)NP * E * 4);
    unsigned int*   part = (unsigned int*)alloc((size_t)NP * NCH * 4);
    size_t fixed = o;
    size_t per = (size_t)MP * D * 2;   // 256-aligned
    const int cands[5] = {16, 8, 4, 2, 1};
    int cp = 1;
    for (int i = 0; i < 5; ++i)
        if (fixed + (size_t)cands[i] * per <= ws_size) { cp = cands[i]; break; }
    unsigned short* comp = (unsigned short*)(ws + fixed);

    hipMemsetAsync(cnt, 0, (size_t)NP * N_NODES * 4, stream);
    k_conv_x<<<(N_NODES * D / 4 + 255) / 256, 256, 0, stream>>>(X, Xb);
    k_conv_w<<<NP * 16, 256, 0, stream>>>(w, wt, WT);
    k_bw<<<NP, 256, 0, stream>>>(bias, bias_t, w, wt, bw);
    k_count<<<NP * E / 256, 256, 0, stream>>>(ar, atr, cnt);
    k_scanA<<<NP * NCH, 256, 0, stream>>>(cnt, part);
    k_scanB<<<1, 64, 0, stream>>>(part);
    k_scanC<<<NP * NCH, 256, 0, stream>>>(cnt, part, oc, cur);
    k_scatter<<<NP * E / 256, 256, 0, stream>>>(ar, ac, atr, atc, cur, csr);
    for (int cs = 0; cs < NP; cs += cp) {
        k_agg<<<(cp * MP + 3) / 4, 256, 0, stream>>>(Xb, oc, csr, comp, cs, cp);
        k_gemm<<<MT128, 512, 0, stream>>>(comp, WT, out, cs, cp, cs == 0 ? 1 : 0);
    }
    k_epi<<<N_NODES / 4, 256, 0, stream>>>(out, cnt, bw);
}